// Round 7
// baseline (2806.288 us; speedup 1.0000x reference)
//
#include <hip/hip_runtime.h>
#include <math.h>

#define L_SZ 1024
#define STRIDE_ 32
#define WIN 8
#define PNUM 31

__device__ __forceinline__ float sigf(float x) { return 1.0f / (1.0f + __expf(-x)); }
__device__ __forceinline__ float tanhfast(float x) {
    float ax = fabsf(x);
    float t = __expf(-2.0f * ax);
    return copysignf((1.0f - t) / (1.0f + t), x);
}
__device__ __forceinline__ float dot4(float4 a, float4 b) {
    return a.x * b.x + a.y * b.y + a.z * b.z + a.w * b.w;
}

// ---------------------------------------------------------------------------
// adjn[i][j] = sigmoid(ew[i][j]) * mask(|i-j|<=8, i!=j) * deg_inv[i]
// ---------------------------------------------------------------------------
__global__ void adj_kernel(const float* __restrict__ ew, float* __restrict__ adjn) {
    int i = threadIdx.x;
    if (i >= 64) return;
    float sum = 0.f;
    for (int j = 0; j < 64; ++j) {
        int d = i - j; d = d < 0 ? -d : d;
        float a = (d <= WIN && d != 0) ? sigf(ew[i * 64 + j]) : 0.f;
        sum += a;
    }
    float dinv = (sum > 0.f) ? 1.0f / sum : 0.f;
    for (int j = 0; j < 64; ++j) {
        int d = i - j; d = d < 0 ? -d : d;
        float a = (d <= WIN && d != 0) ? sigf(ew[i * 64 + j]) : 0.f;
        adjn[i * 64 + j] = a * dinv;
    }
}

// ---------------------------------------------------------------------------
// Fused SAGE1 + SAGE2 + node-sum. One block (256 thr) per (b,p) patch.
// Verified implementation (bit-identical to the independent R4 variant).
// ---------------------------------------------------------------------------
__launch_bounds__(256)
__global__ void sage_simple(const float* __restrict__ I, const float* __restrict__ Q,
                            const float* __restrict__ adjn,
                            const float* __restrict__ Wn1, const float* __restrict__ bn1,
                            const float* __restrict__ Ws1, const float* __restrict__ bs1,
                            const float* __restrict__ Wn2, const float* __restrict__ bn2,
                            const float* __restrict__ Ws2, const float* __restrict__ bs2,
                            float* __restrict__ feats) {
    __shared__ __align__(16) float s_adj[64 * 64];
    __shared__ __align__(16) float s_x0[64 * 2];
    __shared__ __align__(16) float s_n0[64 * 2];
    __shared__ __align__(16) float s_x1[64 * 68];
    __shared__ __align__(16) float s_n1[64 * 68];
    __shared__ __align__(16) float s_part[4][64];

    const int tid = threadIdx.x;
    const int m = blockIdx.x;
    const int b = m / PNUM, p = m % PNUM;
    const float* Ibase = I + (size_t)b * L_SZ + p * STRIDE_;
    const float* Qbase = Q + (size_t)b * L_SZ + p * STRIDE_;

    for (int e = tid; e < 4096; e += 256) s_adj[e] = adjn[e];
    if (tid < 128) {
        int i = tid >> 1, ch = tid & 1;
        s_x0[i * 2 + ch] = ch ? Qbase[i] : Ibase[i];
    }
    __syncthreads();

    // ---- Phase 1a: n0[i][ch] = sum_j adjn[i][j] * x0[j][ch] ----
    if (tid < 128) {
        int i = tid >> 1, ch = tid & 1;
        int jlo = i - WIN; if (jlo < 0) jlo = 0;
        int jhi = i + WIN; if (jhi > 63) jhi = 63;
        float acc = 0.f;
        for (int j = jlo; j <= jhi; ++j)
            acc += s_adj[i * 64 + j] * s_x0[j * 2 + ch];
        s_n0[i * 2 + ch] = acc;
    }
    __syncthreads();

    // ---- Phase 1b: x1[i][o] = relu(x0·Ws1[o] + n0·Wn1[o] + bs1[o] + bn1[o]) ----
    {
        int o = tid & 63, ib = tid >> 6;
        float2 wsv = ((const float2*)Ws1)[o];
        float2 wnv = ((const float2*)Wn1)[o];
        float bias = bs1[o] + bn1[o];
        #pragma unroll
        for (int k = 0; k < 16; ++k) {
            int i = ib * 16 + k;
            float v = bias + wsv.x * s_x0[i * 2] + wsv.y * s_x0[i * 2 + 1]
                           + wnv.x * s_n0[i * 2] + wnv.y * s_n0[i * 2 + 1];
            s_x1[i * 68 + o] = fmaxf(v, 0.f);
        }
    }
    __syncthreads();

    // ---- Phase 1c: n1[i][o] = sum_j adjn[i][j] * x1[j][o] ----
    {
        int ib = tid >> 6, o = tid & 63;
        float nacc[16];
        #pragma unroll
        for (int ii = 0; ii < 16; ++ii) nacc[ii] = 0.f;
        int jlo = 16 * ib - WIN;      if (jlo < 0) jlo = 0;
        int jhi = 16 * ib + 15 + WIN; if (jhi > 63) jhi = 63;
        for (int j = jlo; j <= jhi; ++j) {
            float xjo = s_x1[j * 68 + o];
            #pragma unroll
            for (int ii = 0; ii < 16; ++ii)
                nacc[ii] += s_adj[(16 * ib + ii) * 64 + j] * xjo;
        }
        #pragma unroll
        for (int ii = 0; ii < 16; ++ii)
            s_n1[(16 * ib + ii) * 68 + o] = nacc[ii];
    }
    __syncthreads();

    // ---- Phase 2: out2[i][o] = relu(x1[i]·Ws2[o] + n1[i]·Wn2[o] + b[o]); sum over i ----
    {
        int ib = tid >> 6, o = tid & 63;
        float acc[16];
        #pragma unroll
        for (int ii = 0; ii < 16; ++ii) acc[ii] = 0.f;
        const float4* ws4 = (const float4*)(Ws2 + (size_t)o * 64);
        const float4* wn4 = (const float4*)(Wn2 + (size_t)o * 64);
        #pragma unroll 4
        for (int c = 0; c < 16; ++c) {
            float4 w_s = ws4[c];
            float4 w_n = wn4[c];
            #pragma unroll
            for (int ii = 0; ii < 16; ++ii) {
                int i = ib * 16 + ii;
                float4 xv = *(const float4*)&s_x1[i * 68 + 4 * c];
                float4 nv = *(const float4*)&s_n1[i * 68 + 4 * c];
                acc[ii] += dot4(xv, w_s) + dot4(nv, w_n);
            }
        }
        float bo = bs2[o] + bn2[o];
        float ssum = 0.f;
        #pragma unroll
        for (int ii = 0; ii < 16; ++ii) ssum += fmaxf(acc[ii] + bo, 0.f);
        s_part[ib][o] = ssum;
    }
    __syncthreads();
    if (tid < 64)
        feats[(size_t)m * 64 + tid] =
            s_part[0][tid] + s_part[1][tid] + s_part[2][tid] + s_part[3][tid];
}

// ---------------------------------------------------------------------------
// LSTM layer 0 with fused x-gate GEMV. Writes out0 [B,31,128].
// ---------------------------------------------------------------------------
__launch_bounds__(256)
__global__ void lstm0_fused(const float* __restrict__ feats,
                            const float* __restrict__ Wih, const float* __restrict__ Whh,
                            const float* __restrict__ bih, const float* __restrict__ bhh,
                            float* __restrict__ out0) {
    __shared__ float s_x[4][64];
    __shared__ float s_h[4][128];
    __shared__ float s_c[4][128];
    __shared__ float s_g[4][512];
    const int tid = threadIdx.x;
    const int b0 = blockIdx.x * 4;

    for (int e = tid; e < 512; e += 256) { ((float*)s_h)[e] = 0.f; ((float*)s_c)[e] = 0.f; }
    const float bias0 = bih[tid] + bhh[tid];
    const float bias1 = bih[tid + 256] + bhh[tid + 256];
    const float* wx0 = Wih + (size_t)tid * 64;
    const float* wx1 = Wih + (size_t)(tid + 256) * 64;
    const float* wh0 = Whh + (size_t)tid * 128;
    const float* wh1 = Whh + (size_t)(tid + 256) * 128;
    __syncthreads();

    for (int t = 0; t < 31; ++t) {
        {
            int r = tid >> 6, d = tid & 63;
            s_x[r][d] = feats[((size_t)(b0 + r) * PNUM + t) * 64 + d];
        }
        __syncthreads();

        float acc0[4], acc1[4];
        #pragma unroll
        for (int r = 0; r < 4; ++r) { acc0[r] = bias0; acc1[r] = bias1; }
        #pragma unroll 4
        for (int k = 0; k < 64; ++k) {
            float w0 = wx0[k], w1 = wx1[k];
            #pragma unroll
            for (int r = 0; r < 4; ++r) {
                float xv = s_x[r][k];
                acc0[r] += xv * w0; acc1[r] += xv * w1;
            }
        }
        #pragma unroll 4
        for (int k = 0; k < 128; ++k) {
            float w0 = wh0[k], w1 = wh1[k];
            #pragma unroll
            for (int r = 0; r < 4; ++r) {
                float hv = s_h[r][k];
                acc0[r] += hv * w0; acc1[r] += hv * w1;
            }
        }
        #pragma unroll
        for (int r = 0; r < 4; ++r) { s_g[r][tid] = acc0[r]; s_g[r][tid + 256] = acc1[r]; }
        __syncthreads();

        #pragma unroll
        for (int q = 0; q < 2; ++q) {
            int idx = tid + q * 256;
            int r = idx >> 7, u = idx & 127;
            float gi = s_g[r][u], gf = s_g[r][128 + u];
            float gg = s_g[r][256 + u], go = s_g[r][384 + u];
            float c = sigf(gf) * s_c[r][u] + sigf(gi) * tanhfast(gg);
            float h = sigf(go) * tanhfast(c);
            s_c[r][u] = c;
            s_h[r][u] = h;
            out0[((size_t)(b0 + r) * PNUM + t) * 128 + u] = h;
        }
        __syncthreads();
    }
}

// ---------------------------------------------------------------------------
// LSTM layer 1 + classifier. Writes d_out [B,11] as FLOAT32 (reference dtype).
// ---------------------------------------------------------------------------
__launch_bounds__(256)
__global__ void lstm1_fused(const float* __restrict__ out0,
                            const float* __restrict__ Wih, const float* __restrict__ Whh,
                            const float* __restrict__ bih, const float* __restrict__ bhh,
                            const float* __restrict__ Wc1, const float* __restrict__ bc1,
                            const float* __restrict__ Wc2, const float* __restrict__ bc2,
                            float* __restrict__ out) {
    __shared__ float s_x[4][128];
    __shared__ float s_h[4][128];
    __shared__ float s_c[4][128];
    __shared__ float s_g[4][512];
    __shared__ float s_hid[4][64];
    const int tid = threadIdx.x;
    const int b0 = blockIdx.x * 4;

    for (int e = tid; e < 512; e += 256) { ((float*)s_h)[e] = 0.f; ((float*)s_c)[e] = 0.f; }
    const float bias0 = bih[tid] + bhh[tid];
    const float bias1 = bih[tid + 256] + bhh[tid + 256];
    const float* wx0 = Wih + (size_t)tid * 128;
    const float* wx1 = Wih + (size_t)(tid + 256) * 128;
    const float* wh0 = Whh + (size_t)tid * 128;
    const float* wh1 = Whh + (size_t)(tid + 256) * 128;
    __syncthreads();

    for (int t = 0; t < 31; ++t) {
        #pragma unroll
        for (int q = 0; q < 2; ++q) {
            int idx = tid + q * 256;
            int r = idx >> 7, k = idx & 127;
            s_x[r][k] = out0[((size_t)(b0 + r) * PNUM + t) * 128 + k];
        }
        __syncthreads();

        float acc0[4], acc1[4];
        #pragma unroll
        for (int r = 0; r < 4; ++r) { acc0[r] = bias0; acc1[r] = bias1; }
        #pragma unroll 4
        for (int k = 0; k < 128; ++k) {
            float w0 = wx0[k], w1 = wx1[k];
            #pragma unroll
            for (int r = 0; r < 4; ++r) {
                float xv = s_x[r][k];
                acc0[r] += xv * w0; acc1[r] += xv * w1;
            }
        }
        #pragma unroll 4
        for (int k = 0; k < 128; ++k) {
            float w0 = wh0[k], w1 = wh1[k];
            #pragma unroll
            for (int r = 0; r < 4; ++r) {
                float hv = s_h[r][k];
                acc0[r] += hv * w0; acc1[r] += hv * w1;
            }
        }
        #pragma unroll
        for (int r = 0; r < 4; ++r) { s_g[r][tid] = acc0[r]; s_g[r][tid + 256] = acc1[r]; }
        __syncthreads();

        #pragma unroll
        for (int q = 0; q < 2; ++q) {
            int idx = tid + q * 256;
            int r = idx >> 7, u = idx & 127;
            float gi = s_g[r][u], gf = s_g[r][128 + u];
            float gg = s_g[r][256 + u], go = s_g[r][384 + u];
            float c = sigf(gf) * s_c[r][u] + sigf(gi) * tanhfast(gg);
            float h = sigf(go) * tanhfast(c);
            s_c[r][u] = c;
            s_h[r][u] = h;
        }
        __syncthreads();
    }

    // classifier: hid = relu(h @ Wc1^T + bc1); out = hid @ Wc2^T + bc2
    {
        int r = tid >> 6, u = tid & 63;
        float acc = bc1[u];
        const float* w = Wc1 + (size_t)u * 128;
        #pragma unroll 8
        for (int k = 0; k < 128; ++k) acc += w[k] * s_h[r][k];
        s_hid[r][u] = fmaxf(acc, 0.f);
    }
    __syncthreads();
    if (tid < 44) {
        int r = tid / 11, c = tid % 11;
        float acc = bc2[c];
        #pragma unroll
        for (int u = 0; u < 64; ++u) acc += Wc2[c * 64 + u] * s_hid[r][u];
        out[(size_t)(b0 + r) * 11 + c] = acc;   // fp32 — the reference's output dtype
    }
}

// ---------------------------------------------------------------------------
extern "C" void kernel_launch(void* const* d_in, const int* in_sizes, int n_in,
                              void* d_out, int out_size, void* d_ws, size_t ws_size,
                              hipStream_t stream) {
    (void)in_sizes; (void)n_in; (void)out_size; (void)ws_size;
    const float* I    = (const float*)d_in[0];
    const float* Q    = (const float*)d_in[1];
    const float* ew   = (const float*)d_in[2];
    const float* Wn1  = (const float*)d_in[3];
    const float* bn1  = (const float*)d_in[4];
    const float* Ws1  = (const float*)d_in[5];
    const float* bs1  = (const float*)d_in[6];
    const float* Wn2  = (const float*)d_in[7];
    const float* bn2  = (const float*)d_in[8];
    const float* Ws2  = (const float*)d_in[9];
    const float* bs2  = (const float*)d_in[10];
    const float* Wih0 = (const float*)d_in[11];
    const float* Whh0 = (const float*)d_in[12];
    const float* bih0 = (const float*)d_in[13];
    const float* bhh0 = (const float*)d_in[14];
    const float* Wih1 = (const float*)d_in[15];
    const float* Whh1 = (const float*)d_in[16];
    const float* bih1 = (const float*)d_in[17];
    const float* bhh1 = (const float*)d_in[18];
    const float* Wc1  = (const float*)d_in[19];
    const float* bc1  = (const float*)d_in[20];
    const float* Wc2  = (const float*)d_in[21];
    const float* bc2  = (const float*)d_in[22];
    float* out = (float*)d_out;

    // workspace layout (floats): adjn 4096 | feats 2031616 | out0 4063232
    float* wsp   = (float*)d_ws;
    float* adjn  = wsp;
    float* feats = adjn + 4096;
    float* out0  = feats + 2031616;

    adj_kernel<<<1, 64, 0, stream>>>(ew, adjn);
    sage_simple<<<31744, 256, 0, stream>>>(I, Q, adjn, Wn1, bn1, Ws1, bs1,
                                           Wn2, bn2, Ws2, bs2, feats);
    lstm0_fused<<<256, 256, 0, stream>>>(feats, Wih0, Whh0, bih0, bhh0, out0);
    lstm1_fused<<<256, 256, 0, stream>>>(out0, Wih1, Whh1, bih1, bhh1,
                                         Wc1, bc1, Wc2, bc2, out);
}

// Round 8
// 1432.979 us; speedup vs baseline: 1.9584x; 1.9584x over previous
//
#include <hip/hip_runtime.h>
#include <math.h>

#define L_SZ 1024
#define STRIDE_ 32
#define WIN 8
#define PNUM 31

#define XSTR 68     // x1/n1/ws/wn row stride in floats (17 float4)
#define XSTR4 17
#define ASTR 20     // banded adj row stride (cols map to j = (i&~3)-8+col)

__device__ __forceinline__ float sigf(float x) { return 1.0f / (1.0f + __expf(-x)); }
__device__ __forceinline__ float tanhfast(float x) {
    float ax = fabsf(x);
    float t = __expf(-2.0f * ax);
    return copysignf((1.0f - t) / (1.0f + t), x);
}
__device__ __forceinline__ float dot4(float4 a, float4 b) {
    return a.x * b.x + a.y * b.y + a.z * b.z + a.w * b.w;
}
__device__ __forceinline__ void fma4(float4& acc, float s, float4 v) {
    acc.x += s * v.x; acc.y += s * v.y; acc.z += s * v.z; acc.w += s * v.w;
}

// ---------------------------------------------------------------------------
// adjn[i][j] = sigmoid(ew[i][j]) * mask(|i-j|<=8, i!=j) * deg_inv[i]
// ---------------------------------------------------------------------------
__global__ void adj_kernel(const float* __restrict__ ew, float* __restrict__ adjn) {
    int i = threadIdx.x;
    if (i >= 64) return;
    float sum = 0.f;
    for (int j = 0; j < 64; ++j) {
        int d = i - j; d = d < 0 ? -d : d;
        float a = (d <= WIN && d != 0) ? sigf(ew[i * 64 + j]) : 0.f;
        sum += a;
    }
    float dinv = (sum > 0.f) ? 1.0f / sum : 0.f;
    for (int j = 0; j < 64; ++j) {
        int d = i - j; d = d < 0 ? -d : d;
        float a = (d <= WIN && d != 0) ? sigf(ew[i * 64 + j]) : 0.f;
        adjn[i * 64 + j] = a * dinv;
    }
}

// ---------------------------------------------------------------------------
// prep: LSTM weight transposes WT[k][512] <- W[512][k-dim]. 896 blocks.
// ---------------------------------------------------------------------------
__global__ void prep_kernel(const float* __restrict__ Wih0, const float* __restrict__ Whh0,
                            const float* __restrict__ Wih1, const float* __restrict__ Whh1,
                            float* __restrict__ Wih0T, float* __restrict__ Whh0T,
                            float* __restrict__ Wih1T, float* __restrict__ Whh1T) {
    int e = blockIdx.x * 256 + threadIdx.x;
    if (e < 32768) {                 // Wih0T [64][512]
        int k = e >> 9, j = e & 511;
        Wih0T[e] = Wih0[j * 64 + k];
    } else if (e < 98304) {          // Whh0T [128][512]
        int q = e - 32768; int k = q >> 9, j = q & 511;
        Whh0T[q] = Whh0[j * 128 + k];
    } else if (e < 163840) {         // Wih1T [128][512]
        int q = e - 98304; int k = q >> 9, j = q & 511;
        Wih1T[q] = Wih1[j * 128 + k];
    } else if (e < 229376) {         // Whh1T [128][512]
        int q = e - 163840; int k = q >> 9, j = q & 511;
        Whh1T[q] = Whh1[j * 128 + k];
    }
}

// ---------------------------------------------------------------------------
// Fused SAGE1 + SAGE2 + node-sum: one block per (b,p). [R4 kernel — verified
// bit-identical output to the passing R7 sage.] LDS instrs/wave ~300 vs 950.
// ---------------------------------------------------------------------------
__launch_bounds__(256, 2)
__global__ void sage_kernel(const float* __restrict__ I, const float* __restrict__ Q,
                            const float* __restrict__ adjn,
                            const float* __restrict__ Wn1, const float* __restrict__ bn1,
                            const float* __restrict__ Ws1, const float* __restrict__ bs1,
                            const float* __restrict__ Wn2, const float* __restrict__ bn2,
                            const float* __restrict__ Ws2, const float* __restrict__ bs2,
                            float* __restrict__ feats) {
    __shared__ __align__(16) float s_adj[64 * ASTR];  // banded adjn
    __shared__ __align__(16) float s_x0[64 * 2];
    __shared__ __align__(16) float s_n0[64 * 2];
    __shared__ __align__(16) float s_x1[64 * XSTR];
    __shared__ __align__(16) float s_n1[64 * XSTR];
    __shared__ __align__(16) float s_ws[64 * XSTR];   // Ws2, chunk-XOR-swizzled
    __shared__ __align__(16) float s_wn[64 * XSTR];   // Wn2, chunk-XOR-swizzled
    __shared__ __align__(16) float s_red[4 * 64];

    const int tid = threadIdx.x;
    const int m = blockIdx.x;
    const int b = m / PNUM, p = m % PNUM;
    const float* Ibase = I + (size_t)b * L_SZ + p * STRIDE_;
    const float* Qbase = Q + (size_t)b * L_SZ + p * STRIDE_;

    // ---- Phase 0: stage adj (banded), patch, swizzled layer-2 weights ----
    for (int e = tid; e < 64 * ASTR; e += 256) {
        int i = e / ASTR, c = e % ASTR;
        int j = (i & ~3) - 8 + c;
        s_adj[e] = (j >= 0 && j < 64) ? adjn[i * 64 + j] : 0.f;
    }
    if (tid < 128) {
        int i = tid >> 1, ch = tid & 1;
        s_x0[i * 2 + ch] = ch ? Qbase[i] : Ibase[i];
    }
    {
        const float4* gs = (const float4*)Ws2;
        const float4* gn = (const float4*)Wn2;
        for (int e = tid; e < 1024; e += 256) {
            int o = e >> 4, c = e & 15;
            int cc = c ^ ((o >> 2) & 7);
            ((float4*)s_ws)[o * XSTR4 + cc] = gs[e];
            ((float4*)s_wn)[o * XSTR4 + cc] = gn[e];
        }
    }
    __syncthreads();

    // ---- Phase 1a: n0[i][ch] = sum_j adjn[i][j] * x0[j][ch] ----
    if (tid < 128) {
        int i = tid >> 1, ch = tid & 1;
        int colbase = i & 3;
        float acc = 0.f;
        #pragma unroll
        for (int cc = 0; cc <= 2 * WIN; ++cc) {
            float a = s_adj[i * ASTR + colbase + cc];
            int j = i - WIN + cc;
            j = min(max(j, 0), 63);
            acc += a * s_x0[j * 2 + ch];
        }
        s_n0[i * 2 + ch] = acc;
    }
    __syncthreads();

    // ---- Phase 1b: x1[i][o] = relu(x0 Ws1^T + n0 Wn1^T + bs1 + bn1) ----
    {
        int o = tid & 63, ib = tid >> 6;
        float2 ws = ((const float2*)Ws1)[o];
        float2 wn = ((const float2*)Wn1)[o];
        float bias = bs1[o] + bn1[o];
        #pragma unroll
        for (int k = 0; k < 16; ++k) {
            int i = ib * 16 + k;
            float v = bias + ws.x * s_x0[i * 2] + ws.y * s_x0[i * 2 + 1]
                           + wn.x * s_n0[i * 2] + wn.y * s_n0[i * 2 + 1];
            s_x1[i * XSTR + o] = fmaxf(v, 0.f);
        }
    }
    __syncthreads();

    // ---- Phase 1c: n1 = adjn @ x1 (banded), 4x4 register tiles ----
    {
        int ti = tid >> 4, to = tid & 15;
        int i0 = ti * 4;
        float4 acc4[4];
        #pragma unroll
        for (int ii = 0; ii < 4; ++ii) acc4[ii] = make_float4(0.f, 0.f, 0.f, 0.f);
        #pragma unroll
        for (int c = 0; c < 5; ++c) {
            float4 av[4];
            #pragma unroll
            for (int ii = 0; ii < 4; ++ii)
                av[ii] = *(const float4*)&s_adj[(i0 + ii) * ASTR + 4 * c];
            float4 xv[4];
            #pragma unroll
            for (int jj = 0; jj < 4; ++jj) {
                int r = i0 - 8 + 4 * c + jj;
                r = min(max(r, 0), 63);           // clamped rows pair with adj==0
                xv[jj] = ((const float4*)s_x1)[r * XSTR4 + to];
            }
            #pragma unroll
            for (int ii = 0; ii < 4; ++ii) {
                fma4(acc4[ii], av[ii].x, xv[0]);
                fma4(acc4[ii], av[ii].y, xv[1]);
                fma4(acc4[ii], av[ii].z, xv[2]);
                fma4(acc4[ii], av[ii].w, xv[3]);
            }
        }
        #pragma unroll
        for (int ii = 0; ii < 4; ++ii)
            ((float4*)s_n1)[(i0 + ii) * XSTR4 + to] = acc4[ii];
    }
    __syncthreads();

    // ---- Phase 2: out2 = relu(x1 Ws2^T + n1 Wn2^T + b), then sum over i ----
    {
        int ti = tid >> 4, to = tid & 15;   // i = 4*ti+ii, o = 4*to+oo
        int swz = to & 7;
        float acc[4][4];
        #pragma unroll
        for (int ii = 0; ii < 4; ++ii)
            #pragma unroll
            for (int oo = 0; oo < 4; ++oo) acc[ii][oo] = 0.f;

        for (int c = 0; c < 16; ++c) {
            float4 xv[4], nv[4];
            #pragma unroll
            for (int ii = 0; ii < 4; ++ii) {
                xv[ii] = ((const float4*)s_x1)[(4 * ti + ii) * XSTR4 + c];
                nv[ii] = ((const float4*)s_n1)[(4 * ti + ii) * XSTR4 + c];
            }
            int cc = c ^ swz;
            float4 wsv[4], wnv[4];
            #pragma unroll
            for (int oo = 0; oo < 4; ++oo) {
                wsv[oo] = ((const float4*)s_ws)[(4 * to + oo) * XSTR4 + cc];
                wnv[oo] = ((const float4*)s_wn)[(4 * to + oo) * XSTR4 + cc];
            }
            #pragma unroll
            for (int ii = 0; ii < 4; ++ii)
                #pragma unroll
                for (int oo = 0; oo < 4; ++oo)
                    acc[ii][oo] += dot4(xv[ii], wsv[oo]) + dot4(nv[ii], wnv[oo]);
        }

        // epilogue: bias + relu + sum over i, reduce across ti
        float part[4];
        #pragma unroll
        for (int oo = 0; oo < 4; ++oo) {
            float bsum = bs2[4 * to + oo] + bn2[4 * to + oo];
            float s = 0.f;
            #pragma unroll
            for (int ii = 0; ii < 4; ++ii) s += fmaxf(acc[ii][oo] + bsum, 0.f);
            s += __shfl_xor(s, 16);
            s += __shfl_xor(s, 32);
            part[oo] = s;
        }
        int wave = tid >> 6, lane = tid & 63;
        if (lane < 16) {
            #pragma unroll
            for (int oo = 0; oo < 4; ++oo)
                s_red[wave * 64 + lane * 4 + oo] = part[oo];
        }
    }
    __syncthreads();
    if (tid < 64) {
        float s = s_red[tid] + s_red[64 + tid] + s_red[128 + tid] + s_red[192 + tid];
        feats[(size_t)m * 64 + tid] = s;
    }
}

// ---------------------------------------------------------------------------
// LSTM layer 0, coalesced transposed-weight streams. Writes out0 [B,31,128].
// ---------------------------------------------------------------------------
__launch_bounds__(256)
__global__ void lstm0_fused(const float* __restrict__ feats,
                            const float* __restrict__ WihT, const float* __restrict__ WhhT,
                            const float* __restrict__ bih, const float* __restrict__ bhh,
                            float* __restrict__ out0) {
    __shared__ float s_x[4][64];
    __shared__ float s_h[4][128];
    __shared__ float s_c[4][128];
    __shared__ float s_g[4][512];
    const int tid = threadIdx.x;
    const int b0 = blockIdx.x * 4;

    for (int e = tid; e < 512; e += 256) { ((float*)s_h)[e] = 0.f; ((float*)s_c)[e] = 0.f; }
    const float bias0 = bih[tid] + bhh[tid];
    const float bias1 = bih[tid + 256] + bhh[tid + 256];
    __syncthreads();

    for (int t = 0; t < 31; ++t) {
        {
            int r = tid >> 6, d = tid & 63;
            s_x[r][d] = feats[((size_t)(b0 + r) * PNUM + t) * 64 + d];
        }
        __syncthreads();

        float acc0[4], acc1[4];
        #pragma unroll
        for (int r = 0; r < 4; ++r) { acc0[r] = bias0; acc1[r] = bias1; }
        #pragma unroll 4
        for (int k = 0; k < 64; ++k) {
            float w0 = WihT[(size_t)k * 512 + tid];          // coalesced
            float w1 = WihT[(size_t)k * 512 + 256 + tid];
            #pragma unroll
            for (int r = 0; r < 4; ++r) {
                float xv = s_x[r][k];
                acc0[r] += xv * w0; acc1[r] += xv * w1;
            }
        }
        #pragma unroll 4
        for (int k = 0; k < 128; ++k) {
            float w0 = WhhT[(size_t)k * 512 + tid];          // coalesced
            float w1 = WhhT[(size_t)k * 512 + 256 + tid];
            #pragma unroll
            for (int r = 0; r < 4; ++r) {
                float hv = s_h[r][k];
                acc0[r] += hv * w0; acc1[r] += hv * w1;
            }
        }
        #pragma unroll
        for (int r = 0; r < 4; ++r) { s_g[r][tid] = acc0[r]; s_g[r][tid + 256] = acc1[r]; }
        __syncthreads();

        #pragma unroll
        for (int q = 0; q < 2; ++q) {
            int idx = tid + q * 256;
            int r = idx >> 7, u = idx & 127;
            float gi = s_g[r][u], gf = s_g[r][128 + u];
            float gg = s_g[r][256 + u], go = s_g[r][384 + u];
            float c = sigf(gf) * s_c[r][u] + sigf(gi) * tanhfast(gg);
            float h = sigf(go) * tanhfast(c);
            s_c[r][u] = c;
            s_h[r][u] = h;
            out0[((size_t)(b0 + r) * PNUM + t) * 128 + u] = h;
        }
        __syncthreads();
    }
}

// ---------------------------------------------------------------------------
// LSTM layer 1 + classifier, coalesced transposed-weight streams. fp32 out.
// ---------------------------------------------------------------------------
__launch_bounds__(256)
__global__ void lstm1_fused(const float* __restrict__ out0,
                            const float* __restrict__ WihT, const float* __restrict__ WhhT,
                            const float* __restrict__ bih, const float* __restrict__ bhh,
                            const float* __restrict__ Wc1, const float* __restrict__ bc1,
                            const float* __restrict__ Wc2, const float* __restrict__ bc2,
                            float* __restrict__ out) {
    __shared__ float s_x[4][128];
    __shared__ float s_h[4][128];
    __shared__ float s_c[4][128];
    __shared__ float s_g[4][512];
    __shared__ float s_hid[4][64];
    const int tid = threadIdx.x;
    const int b0 = blockIdx.x * 4;

    for (int e = tid; e < 512; e += 256) { ((float*)s_h)[e] = 0.f; ((float*)s_c)[e] = 0.f; }
    const float bias0 = bih[tid] + bhh[tid];
    const float bias1 = bih[tid + 256] + bhh[tid + 256];
    __syncthreads();

    for (int t = 0; t < 31; ++t) {
        #pragma unroll
        for (int q = 0; q < 2; ++q) {
            int idx = tid + q * 256;
            int r = idx >> 7, k = idx & 127;
            s_x[r][k] = out0[((size_t)(b0 + r) * PNUM + t) * 128 + k];
        }
        __syncthreads();

        float acc0[4], acc1[4];
        #pragma unroll
        for (int r = 0; r < 4; ++r) { acc0[r] = bias0; acc1[r] = bias1; }
        #pragma unroll 4
        for (int k = 0; k < 128; ++k) {
            float w0 = WihT[(size_t)k * 512 + tid];          // coalesced
            float w1 = WihT[(size_t)k * 512 + 256 + tid];
            #pragma unroll
            for (int r = 0; r < 4; ++r) {
                float xv = s_x[r][k];
                acc0[r] += xv * w0; acc1[r] += xv * w1;
            }
        }
        #pragma unroll 4
        for (int k = 0; k < 128; ++k) {
            float w0 = WhhT[(size_t)k * 512 + tid];          // coalesced
            float w1 = WhhT[(size_t)k * 512 + 256 + tid];
            #pragma unroll
            for (int r = 0; r < 4; ++r) {
                float hv = s_h[r][k];
                acc0[r] += hv * w0; acc1[r] += hv * w1;
            }
        }
        #pragma unroll
        for (int r = 0; r < 4; ++r) { s_g[r][tid] = acc0[r]; s_g[r][tid + 256] = acc1[r]; }
        __syncthreads();

        #pragma unroll
        for (int q = 0; q < 2; ++q) {
            int idx = tid + q * 256;
            int r = idx >> 7, u = idx & 127;
            float gi = s_g[r][u], gf = s_g[r][128 + u];
            float gg = s_g[r][256 + u], go = s_g[r][384 + u];
            float c = sigf(gf) * s_c[r][u] + sigf(gi) * tanhfast(gg);
            float h = sigf(go) * tanhfast(c);
            s_c[r][u] = c;
            s_h[r][u] = h;
        }
        __syncthreads();
    }

    // classifier: hid = relu(h @ Wc1^T + bc1); out = hid @ Wc2^T + bc2
    {
        int r = tid >> 6, u = tid & 63;
        float acc = bc1[u];
        const float* w = Wc1 + (size_t)u * 128;
        #pragma unroll 8
        for (int k = 0; k < 128; ++k) acc += w[k] * s_h[r][k];
        s_hid[r][u] = fmaxf(acc, 0.f);
    }
    __syncthreads();
    if (tid < 44) {
        int r = tid / 11, c = tid % 11;
        float acc = bc2[c];
        #pragma unroll
        for (int u = 0; u < 64; ++u) acc += Wc2[c * 64 + u] * s_hid[r][u];
        out[(size_t)(b0 + r) * 11 + c] = acc;
    }
}

// ---------------------------------------------------------------------------
extern "C" void kernel_launch(void* const* d_in, const int* in_sizes, int n_in,
                              void* d_out, int out_size, void* d_ws, size_t ws_size,
                              hipStream_t stream) {
    (void)in_sizes; (void)n_in; (void)out_size; (void)ws_size;
    const float* I    = (const float*)d_in[0];
    const float* Q    = (const float*)d_in[1];
    const float* ew   = (const float*)d_in[2];
    const float* Wn1  = (const float*)d_in[3];
    const float* bn1  = (const float*)d_in[4];
    const float* Ws1  = (const float*)d_in[5];
    const float* bs1  = (const float*)d_in[6];
    const float* Wn2  = (const float*)d_in[7];
    const float* bn2  = (const float*)d_in[8];
    const float* Ws2  = (const float*)d_in[9];
    const float* bs2  = (const float*)d_in[10];
    const float* Wih0 = (const float*)d_in[11];
    const float* Whh0 = (const float*)d_in[12];
    const float* bih0 = (const float*)d_in[13];
    const float* bhh0 = (const float*)d_in[14];
    const float* Wih1 = (const float*)d_in[15];
    const float* Whh1 = (const float*)d_in[16];
    const float* bih1 = (const float*)d_in[17];
    const float* bhh1 = (const float*)d_in[18];
    const float* Wc1  = (const float*)d_in[19];
    const float* bc1  = (const float*)d_in[20];
    const float* Wc2  = (const float*)d_in[21];
    const float* bc2  = (const float*)d_in[22];
    float* out = (float*)d_out;

    // workspace (floats): adjn 4096 | WihT0 32768 | WhhT0 65536 | WihT1 65536
    //                   | WhhT1 65536 | feats 2031616 | out0 4063232  (~25.3 MB)
    float* wsp   = (float*)d_ws;
    float* adjn  = wsp;
    float* WihT0 = adjn  + 4096;
    float* WhhT0 = WihT0 + 32768;
    float* WihT1 = WhhT0 + 65536;
    float* WhhT1 = WihT1 + 65536;
    float* feats = WhhT1 + 65536;
    float* out0  = feats + 2031616;

    adj_kernel<<<1, 64, 0, stream>>>(ew, adjn);
    prep_kernel<<<896, 256, 0, stream>>>(Wih0, Whh0, Wih1, Whh1,
                                         WihT0, WhhT0, WihT1, WhhT1);
    sage_kernel<<<31744, 256, 0, stream>>>(I, Q, adjn, Wn1, bn1, Ws1, bs1,
                                           Wn2, bn2, Ws2, bs2, feats);
    lstm0_fused<<<256, 256, 0, stream>>>(feats, WihT0, WhhT0, bih0, bhh0, out0);
    lstm1_fused<<<256, 256, 0, stream>>>(out0, WihT1, WhhT1, bih1, bhh1,
                                         Wc1, bc1, Wc2, bc2, out);
}

// Round 10
// 972.512 us; speedup vs baseline: 2.8856x; 1.4735x over previous
//
#include <hip/hip_runtime.h>
#include <hip/hip_bf16.h>
#include <math.h>

#define L_SZ 1024
#define STRIDE_ 32
#define WIN 8
#define PNUM 31

// LDS row strides (in shorts). All rows 16B-aligned; dword strides = 36/68 = 4 mod 32
// -> frag reads are 2-way-per-bank balanced (free per m136).
#define ADJS 72
#define X1TS 72
#define WHS  136
#define CAS  136

typedef __attribute__((ext_vector_type(8))) short short8;
typedef __attribute__((ext_vector_type(4))) short short4v;
typedef __attribute__((ext_vector_type(4))) float f32x4;

#define MFMA16(a, b, c) __builtin_amdgcn_mfma_f32_16x16x32_bf16(a, b, c, 0, 0, 0)

__device__ __forceinline__ float sigf(float x) { return 1.0f / (1.0f + __expf(-x)); }
__device__ __forceinline__ float tanhfast(float x) {
    float ax = fabsf(x);
    float t = __expf(-2.0f * ax);
    return copysignf((1.0f - t) / (1.0f + t), x);
}
__device__ __forceinline__ short f2bf(float f) {
    __hip_bfloat16 h = __float2bfloat16(f);   // RNE
    return *reinterpret_cast<short*>(&h);
}
__device__ __forceinline__ float bf2f(short s) {
    __hip_bfloat16 h = *reinterpret_cast<__hip_bfloat16*>(&s);
    return __bfloat162float(h);
}

// ---------------------------------------------------------------------------
// adjn[i][j] = sigmoid(ew[i][j]) * mask(|i-j|<=8, i!=j) * deg_inv[i]
// ---------------------------------------------------------------------------
__global__ void adj_kernel(const float* __restrict__ ew, float* __restrict__ adjn) {
    int i = threadIdx.x;
    if (i >= 64) return;
    float sum = 0.f;
    for (int j = 0; j < 64; ++j) {
        int d = i - j; d = d < 0 ? -d : d;
        float a = (d <= WIN && d != 0) ? sigf(ew[i * 64 + j]) : 0.f;
        sum += a;
    }
    float dinv = (sum > 0.f) ? 1.0f / sum : 0.f;
    for (int j = 0; j < 64; ++j) {
        int d = i - j; d = d < 0 ? -d : d;
        float a = (d <= WIN && d != 0) ? sigf(ew[i * 64 + j]) : 0.f;
        adjn[i * 64 + j] = a * dinv;
    }
}

// ---------------------------------------------------------------------------
// prep: LSTM weight transposes WT[k][512] <- W[512][k-dim]. 896 blocks.
// ---------------------------------------------------------------------------
__global__ void prep_kernel(const float* __restrict__ Wih0, const float* __restrict__ Whh0,
                            const float* __restrict__ Wih1, const float* __restrict__ Whh1,
                            float* __restrict__ Wih0T, float* __restrict__ Whh0T,
                            float* __restrict__ Wih1T, float* __restrict__ Whh1T) {
    int e = blockIdx.x * 256 + threadIdx.x;
    if (e < 32768) {
        int k = e >> 9, j = e & 511;
        Wih0T[e] = Wih0[j * 64 + k];
    } else if (e < 98304) {
        int q = e - 32768; int k = q >> 9, j = q & 511;
        Whh0T[q] = Whh0[j * 128 + k];
    } else if (e < 163840) {
        int q = e - 98304; int k = q >> 9, j = q & 511;
        Wih1T[q] = Wih1[j * 128 + k];
    } else if (e < 229376) {
        int q = e - 163840; int k = q >> 9, j = q & 511;
        Whh1T[q] = Whh1[j * 128 + k];
    }
}

// ---------------------------------------------------------------------------
// Fused SAGE via bf16 MFMA, with hi/lo-split layer-2 weights.
// The W split kills the DOMINANT quantization term: eps_W is shared across the
// 64-node sum (correlated, no sqrt-cancellation) — x1/n1/adj errors are
// independent per (i,k) and stay ~6x smaller.
// ---------------------------------------------------------------------------
__launch_bounds__(256, 2)
__global__ void sage_mfma(const float* __restrict__ I, const float* __restrict__ Q,
                          const float* __restrict__ adjn,
                          const float* __restrict__ Wn1, const float* __restrict__ bn1,
                          const float* __restrict__ Ws1, const float* __restrict__ bs1,
                          const float* __restrict__ Wn2, const float* __restrict__ bn2,
                          const float* __restrict__ Ws2, const float* __restrict__ bs2,
                          float* __restrict__ feats) {
    __shared__ __align__(16) short s_adj[64 * ADJS];   // adjn bf16 row-major
    __shared__ __align__(16) short s_wh [64 * WHS];    // wcat hi
    __shared__ __align__(16) short s_whl[64 * WHS];    // wcat lo (residual)
    __shared__ __align__(16) short s_x1T[64 * X1TS];   // x1^T [o][i] bf16
    __shared__ __align__(16) short s_cat[64 * CAS];    // [i][0..63:x1, 64..127:n1] bf16
    __shared__ __align__(16) float s_x0[128];
    __shared__ __align__(16) float s_n0[128];
    __shared__ __align__(16) float s_part[4][64];

    const int tid = threadIdx.x;
    const int m = blockIdx.x;
    const int b = m / PNUM, p = m % PNUM;
    const float* Ibase = I + (size_t)b * L_SZ + p * STRIDE_;
    const float* Qbase = Q + (size_t)b * L_SZ + p * STRIDE_;

    // ---- Phase 0: stage adj(bf16), wcat(hi+lo), x0 ----
    {
        int i = tid >> 2, j0 = (tid & 3) << 4;           // 16 adj elems / thread
        const float4* src = (const float4*)(adjn + i * 64 + j0);
        float4 f0 = src[0], f1 = src[1], f2 = src[2], f3 = src[3];
        union { short s[16]; short8 v[2]; } pk;
        pk.s[0] = f2bf(f0.x); pk.s[1] = f2bf(f0.y); pk.s[2]  = f2bf(f0.z); pk.s[3]  = f2bf(f0.w);
        pk.s[4] = f2bf(f1.x); pk.s[5] = f2bf(f1.y); pk.s[6]  = f2bf(f1.z); pk.s[7]  = f2bf(f1.w);
        pk.s[8] = f2bf(f2.x); pk.s[9] = f2bf(f2.y); pk.s[10] = f2bf(f2.z); pk.s[11] = f2bf(f2.w);
        pk.s[12] = f2bf(f3.x); pk.s[13] = f2bf(f3.y); pk.s[14] = f2bf(f3.z); pk.s[15] = f2bf(f3.w);
        *(short8*)&s_adj[i * ADJS + j0]     = pk.v[0];
        *(short8*)&s_adj[i * ADJS + j0 + 8] = pk.v[1];
    }
    {
        int oo = tid >> 2, k0 = (tid & 3) << 5;          // 32 wcat elems / thread
        for (int c = 0; c < 4; ++c) {
            int k = k0 + c * 8;
            const float* sp = (k < 64) ? (Ws2 + (size_t)oo * 64 + k)
                                       : (Wn2 + (size_t)oo * 64 + (k - 64));
            float4 fa = *(const float4*)sp, fb = *(const float4*)(sp + 4);
            float fv[8] = {fa.x, fa.y, fa.z, fa.w, fb.x, fb.y, fb.z, fb.w};
            union { short s[8]; short8 v; } ph, pl;
            #pragma unroll
            for (int t = 0; t < 8; ++t) {
                short hi = f2bf(fv[t]);
                ph.s[t] = hi;
                pl.s[t] = f2bf(fv[t] - bf2f(hi));        // exact residual, then RNE
            }
            *(short8*)&s_wh [oo * WHS + k] = ph.v;
            *(short8*)&s_whl[oo * WHS + k] = pl.v;
        }
    }
    if (tid < 128) {
        int i = tid >> 1, ch = tid & 1;
        s_x0[i * 2 + ch] = ch ? Qbase[i] : Ibase[i];
    }
    __syncthreads();

    // ---- Phase 1a: n0[i][ch] (exact fp32 adj from global, L2-resident) ----
    if (tid < 128) {
        int i = tid >> 1, ch = tid & 1;
        int jlo = i - WIN; if (jlo < 0) jlo = 0;
        int jhi = i + WIN; if (jhi > 63) jhi = 63;
        float acc = 0.f;
        for (int j = jlo; j <= jhi; ++j)
            acc += adjn[i * 64 + j] * s_x0[j * 2 + ch];
        s_n0[i * 2 + ch] = acc;
    }
    __syncthreads();

    // ---- Phase 1b: x1[i][o] = relu(...), write x1T (scalar) + catA (b128) ----
    {
        int i = tid & 63, oc = tid >> 6;
        float x0a = s_x0[i * 2], x0b = s_x0[i * 2 + 1];
        float n0a = s_n0[i * 2], n0b = s_n0[i * 2 + 1];
        union { short s[16]; short8 v[2]; } pk;
        #pragma unroll
        for (int t = 0; t < 16; ++t) {
            int o = oc * 16 + t;                         // wave-uniform -> s_load
            float2 wsv = ((const float2*)Ws1)[o];
            float2 wnv = ((const float2*)Wn1)[o];
            float v = bs1[o] + bn1[o] + wsv.x * x0a + wsv.y * x0b
                                      + wnv.x * n0a + wnv.y * n0b;
            v = fmaxf(v, 0.f);
            short bv = f2bf(v);
            s_x1T[o * X1TS + i] = bv;                    // transposed copy
            pk.s[t] = bv;
        }
        *(short8*)&s_cat[i * CAS + oc * 16]     = pk.v[0];
        *(short8*)&s_cat[i * CAS + oc * 16 + 8] = pk.v[1];
    }
    __syncthreads();

    const int w = tid >> 6, l = tid & 63, q = l >> 4, l15 = l & 15;

    // ---- MFMA#1: n1^T, band-aware (6 of 8 tile pairs), write into catA ----
    {
        short8 a0 = *(const short8*)&s_x1T[(16 * w + l15) * X1TS + 8 * q];       // ks=0
        short8 a1 = *(const short8*)&s_x1T[(16 * w + l15) * X1TS + 8 * q + 32];  // ks=1
        f32x4 z = {0.f, 0.f, 0.f, 0.f};
        f32x4 c0 = z, c1 = z, c2 = z, c3 = z;
        // B(nt,ks) = adj[col i = l15+16nt][k j = 8q+32ks ..]
        c0 = MFMA16(a0, *(const short8*)&s_adj[(l15 +  0) * ADJS + 8 * q],      c0);
        c1 = MFMA16(a0, *(const short8*)&s_adj[(l15 + 16) * ADJS + 8 * q],      c1);
        c1 = MFMA16(a1, *(const short8*)&s_adj[(l15 + 16) * ADJS + 8 * q + 32], c1);
        c2 = MFMA16(a0, *(const short8*)&s_adj[(l15 + 32) * ADJS + 8 * q],      c2);
        c2 = MFMA16(a1, *(const short8*)&s_adj[(l15 + 32) * ADJS + 8 * q + 32], c2);
        c3 = MFMA16(a1, *(const short8*)&s_adj[(l15 + 48) * ADJS + 8 * q + 32], c3);
        // D: col = i = l15+16nt, rows o = 16w + 4q + reg (consecutive) -> b64 writes
        f32x4 cc[4] = {c0, c1, c2, c3};
        #pragma unroll
        for (int nt = 0; nt < 4; ++nt) {
            short4v nv;
            nv[0] = f2bf(cc[nt][0]); nv[1] = f2bf(cc[nt][1]);
            nv[2] = f2bf(cc[nt][2]); nv[3] = f2bf(cc[nt][3]);
            *(short4v*)&s_cat[(l15 + 16 * nt) * CAS + 64 + 16 * w + 4 * q] = nv;
        }
    }
    __syncthreads();

    // ---- MFMA#2: out2 tile; B = W_hi + W_lo (split accumulate) ----
    {
        short8 a2[4];
        #pragma unroll
        for (int ks = 0; ks < 4; ++ks)
            a2[ks] = *(const short8*)&s_cat[(16 * w + l15) * CAS + 32 * ks + 8 * q];
        f32x4 z = {0.f, 0.f, 0.f, 0.f};
        f32x4 acc2[4] = {z, z, z, z};
        #pragma unroll
        for (int nt = 0; nt < 4; ++nt) {
            #pragma unroll
            for (int ks = 0; ks < 4; ++ks) {
                short8 bhi = *(const short8*)&s_wh [(l15 + 16 * nt) * WHS + 32 * ks + 8 * q];
                short8 blo = *(const short8*)&s_whl[(l15 + 16 * nt) * WHS + 32 * ks + 8 * q];
                acc2[nt] = MFMA16(a2[ks], bhi, acc2[nt]);
                acc2[nt] = MFMA16(a2[ks], blo, acc2[nt]);
            }
        }
        // epilogue: +bias, relu, sum over this wave's 16 rows
        float part[4];
        #pragma unroll
        for (int nt = 0; nt < 4; ++nt) {
            int oo = l15 + 16 * nt;
            float bo = bs2[oo] + bn2[oo];
            float s = fmaxf(acc2[nt][0] + bo, 0.f) + fmaxf(acc2[nt][1] + bo, 0.f)
                    + fmaxf(acc2[nt][2] + bo, 0.f) + fmaxf(acc2[nt][3] + bo, 0.f);
            s += __shfl_xor(s, 16);
            s += __shfl_xor(s, 32);
            part[nt] = s;
        }
        if (l < 16) {
            #pragma unroll
            for (int nt = 0; nt < 4; ++nt)
                s_part[w][l + 16 * nt] = part[nt];
        }
    }
    __syncthreads();
    if (tid < 64)
        feats[(size_t)m * 64 + tid] =
            s_part[0][tid] + s_part[1][tid] + s_part[2][tid] + s_part[3][tid];
}

// ---------------------------------------------------------------------------
// LSTM layer 0 v2: 512 thr (8 waves), one gate/thread, [k][4row] float4 LDS.
// ---------------------------------------------------------------------------
__launch_bounds__(512)
__global__ void lstm0_fused(const float* __restrict__ feats,
                            const float* __restrict__ WihT, const float* __restrict__ WhhT,
                            const float* __restrict__ bih, const float* __restrict__ bhh,
                            float* __restrict__ out0) {
    __shared__ __align__(16) float s_xf[64 * 4];    // [k][r]
    __shared__ __align__(16) float s_hf[128 * 4];   // [k][r]
    __shared__ float s_c[4][128];
    __shared__ float s_g[4][512];
    const int tid = threadIdx.x;
    const int b0 = blockIdx.x * 4;

    s_hf[tid] = 0.f;
    { int r = tid >> 7, u = tid & 127; s_c[r][u] = 0.f; }
    const float bias = bih[tid] + bhh[tid];
    __syncthreads();

    for (int t = 0; t < 31; ++t) {
        if (tid < 256) {
            int r = tid >> 6, d = tid & 63;
            s_xf[d * 4 + r] = feats[((size_t)(b0 + r) * PNUM + t) * 64 + d];
        }
        __syncthreads();

        float a0 = bias, a1 = bias, a2 = bias, a3 = bias;
        const float* wp = WihT + tid;
        #pragma unroll 8
        for (int k = 0; k < 64; ++k) {
            float wv = wp[(size_t)k * 512];
            float4 xv = *(const float4*)&s_xf[k * 4];
            a0 += xv.x * wv; a1 += xv.y * wv; a2 += xv.z * wv; a3 += xv.w * wv;
        }
        const float* hp = WhhT + tid;
        #pragma unroll 8
        for (int k = 0; k < 128; ++k) {
            float wv = hp[(size_t)k * 512];
            float4 hv = *(const float4*)&s_hf[k * 4];
            a0 += hv.x * wv; a1 += hv.y * wv; a2 += hv.z * wv; a3 += hv.w * wv;
        }
        s_g[0][tid] = a0; s_g[1][tid] = a1; s_g[2][tid] = a2; s_g[3][tid] = a3;
        __syncthreads();

        {
            int r = tid >> 7, u = tid & 127;
            float gi = s_g[r][u], gf = s_g[r][128 + u];
            float gg = s_g[r][256 + u], go = s_g[r][384 + u];
            float c = sigf(gf) * s_c[r][u] + sigf(gi) * tanhfast(gg);
            float h = sigf(go) * tanhfast(c);
            s_c[r][u] = c;
            s_hf[u * 4 + r] = h;
            out0[((size_t)(b0 + r) * PNUM + t) * 128 + u] = h;
        }
        __syncthreads();
    }
}

// ---------------------------------------------------------------------------
// LSTM layer 1 v2 + classifier. fp32 out [B,11].
// ---------------------------------------------------------------------------
__launch_bounds__(512)
__global__ void lstm1_fused(const float* __restrict__ out0,
                            const float* __restrict__ WihT, const float* __restrict__ WhhT,
                            const float* __restrict__ bih, const float* __restrict__ bhh,
                            const float* __restrict__ Wc1, const float* __restrict__ bc1,
                            const float* __restrict__ Wc2, const float* __restrict__ bc2,
                            float* __restrict__ out) {
    __shared__ __align__(16) float s_xf[128 * 4];   // [k][r]
    __shared__ __align__(16) float s_hf[128 * 4];   // [k][r]
    __shared__ float s_c[4][128];
    __shared__ float s_g[4][512];
    __shared__ float s_hid[4][64];
    const int tid = threadIdx.x;
    const int b0 = blockIdx.x * 4;

    s_hf[tid] = 0.f;
    { int r = tid >> 7, u = tid & 127; s_c[r][u] = 0.f; }
    const float bias = bih[tid] + bhh[tid];
    __syncthreads();

    for (int t = 0; t < 31; ++t) {
        {
            int r = tid >> 7, k = tid & 127;
            s_xf[k * 4 + r] = out0[((size_t)(b0 + r) * PNUM + t) * 128 + k];
        }
        __syncthreads();

        float a0 = bias, a1 = bias, a2 = bias, a3 = bias;
        const float* wp = WihT + tid;
        #pragma unroll 8
        for (int k = 0; k < 128; ++k) {
            float wv = wp[(size_t)k * 512];
            float4 xv = *(const float4*)&s_xf[k * 4];
            a0 += xv.x * wv; a1 += xv.y * wv; a2 += xv.z * wv; a3 += xv.w * wv;
        }
        const float* hp = WhhT + tid;
        #pragma unroll 8
        for (int k = 0; k < 128; ++k) {
            float wv = hp[(size_t)k * 512];
            float4 hv = *(const float4*)&s_hf[k * 4];
            a0 += hv.x * wv; a1 += hv.y * wv; a2 += hv.z * wv; a3 += hv.w * wv;
        }
        s_g[0][tid] = a0; s_g[1][tid] = a1; s_g[2][tid] = a2; s_g[3][tid] = a3;
        __syncthreads();

        {
            int r = tid >> 7, u = tid & 127;
            float gi = s_g[r][u], gf = s_g[r][128 + u];
            float gg = s_g[r][256 + u], go = s_g[r][384 + u];
            float c = sigf(gf) * s_c[r][u] + sigf(gi) * tanhfast(gg);
            float h = sigf(go) * tanhfast(c);
            s_c[r][u] = c;
            s_hf[u * 4 + r] = h;
        }
        __syncthreads();
    }

    // classifier: hid = relu(h @ Wc1^T + bc1); out = hid @ Wc2^T + bc2
    if (tid < 256) {
        int r = tid >> 6, u = tid & 63;
        float acc = bc1[u];
        const float* wv = Wc1 + (size_t)u * 128;
        #pragma unroll 8
        for (int k = 0; k < 128; ++k) acc += wv[k] * s_hf[k * 4 + r];
        s_hid[r][u] = fmaxf(acc, 0.f);
    }
    __syncthreads();
    if (tid < 44) {
        int r = tid / 11, c = tid % 11;
        float acc = bc2[c];
        #pragma unroll
        for (int u = 0; u < 64; ++u) acc += Wc2[c * 64 + u] * s_hid[r][u];
        out[(size_t)(b0 + r) * 11 + c] = acc;
    }
}

// ---------------------------------------------------------------------------
extern "C" void kernel_launch(void* const* d_in, const int* in_sizes, int n_in,
                              void* d_out, int out_size, void* d_ws, size_t ws_size,
                              hipStream_t stream) {
    (void)in_sizes; (void)n_in; (void)out_size; (void)ws_size;
    const float* I    = (const float*)d_in[0];
    const float* Q    = (const float*)d_in[1];
    const float* ew   = (const float*)d_in[2];
    const float* Wn1  = (const float*)d_in[3];
    const float* bn1  = (const float*)d_in[4];
    const float* Ws1  = (const float*)d_in[5];
    const float* bs1  = (const float*)d_in[6];
    const float* Wn2  = (const float*)d_in[7];
    const float* bn2  = (const float*)d_in[8];
    const float* Ws2  = (const float*)d_in[9];
    const float* bs2  = (const float*)d_in[10];
    const float* Wih0 = (const float*)d_in[11];
    const float* Whh0 = (const float*)d_in[12];
    const float* bih0 = (const float*)d_in[13];
    const float* bhh0 = (const float*)d_in[14];
    const float* Wih1 = (const float*)d_in[15];
    const float* Whh1 = (const float*)d_in[16];
    const float* bih1 = (const float*)d_in[17];
    const float* bhh1 = (const float*)d_in[18];
    const float* Wc1  = (const float*)d_in[19];
    const float* bc1  = (const float*)d_in[20];
    const float* Wc2  = (const float*)d_in[21];
    const float* bc2  = (const float*)d_in[22];
    float* out = (float*)d_out;

    // workspace (floats)
    float* wsp   = (float*)d_ws;
    float* adjn  = wsp;
    float* WihT0 = adjn  + 4096;
    float* WhhT0 = WihT0 + 32768;
    float* WihT1 = WhhT0 + 65536;
    float* WhhT1 = WihT1 + 65536;
    float* feats = WhhT1 + 65536;
    float* out0  = feats + 2031616;

    adj_kernel<<<1, 64, 0, stream>>>(ew, adjn);
    prep_kernel<<<896, 256, 0, stream>>>(Wih0, Whh0, Wih1, Whh1,
                                         WihT0, WhhT0, WihT1, WhhT1);
    sage_mfma<<<31744, 256, 0, stream>>>(I, Q, adjn, Wn1, bn1, Ws1, bs1,
                                         Wn2, bn2, Ws2, bs2, feats);
    lstm0_fused<<<256, 512, 0, stream>>>(feats, WihT0, WhhT0, bih0, bhh0, out0);
    lstm1_fused<<<256, 512, 0, stream>>>(out0, WihT1, WhhT1, bih1, bhh1,
                                         Wc1, bc1, Wc2, bc2, out);
}

// Round 11
// 885.752 us; speedup vs baseline: 3.1683x; 1.0980x over previous
//
#include <hip/hip_runtime.h>
#include <hip/hip_bf16.h>
#include <math.h>

#define L_SZ 1024
#define STRIDE_ 32
#define WIN 8
#define PNUM 31

// LDS row strides (in shorts). dword strides = 36/68 = 4 mod 32 -> 2-way banks (free).
#define X1TS 72
#define CAS  136

typedef __attribute__((ext_vector_type(8))) short short8;
typedef __attribute__((ext_vector_type(4))) short short4v;
typedef __attribute__((ext_vector_type(4))) float f32x4;

#define MFMA16(a, b, c) __builtin_amdgcn_mfma_f32_16x16x32_bf16(a, b, c, 0, 0, 0)

__device__ __forceinline__ float sigf(float x) { return 1.0f / (1.0f + __expf(-x)); }
__device__ __forceinline__ float tanhfast(float x) {
    float ax = fabsf(x);
    float t = __expf(-2.0f * ax);
    return copysignf((1.0f - t) / (1.0f + t), x);
}
__device__ __forceinline__ short f2bf(float f) {
    __hip_bfloat16 h = __float2bfloat16(f);   // RNE
    return *reinterpret_cast<short*>(&h);
}
__device__ __forceinline__ float bf2f(short s) {
    __hip_bfloat16 h = *reinterpret_cast<__hip_bfloat16*>(&s);
    return __bfloat162float(h);
}

// ---------------------------------------------------------------------------
// adjn[i][j] = sigmoid(ew[i][j]) * mask(|i-j|<=8, i!=j) * deg_inv[i]
// ---------------------------------------------------------------------------
__global__ void adj_kernel(const float* __restrict__ ew, float* __restrict__ adjn) {
    int i = threadIdx.x;
    if (i >= 64) return;
    float sum = 0.f;
    for (int j = 0; j < 64; ++j) {
        int d = i - j; d = d < 0 ? -d : d;
        float a = (d <= WIN && d != 0) ? sigf(ew[i * 64 + j]) : 0.f;
        sum += a;
    }
    float dinv = (sum > 0.f) ? 1.0f / sum : 0.f;
    for (int j = 0; j < 64; ++j) {
        int d = i - j; d = d < 0 ? -d : d;
        float a = (d <= WIN && d != 0) ? sigf(ew[i * 64 + j]) : 0.f;
        adjn[i * 64 + j] = a * dinv;
    }
}

// ---------------------------------------------------------------------------
// prep: blocks 0..895 LSTM weight transposes; blocks 896..905: precompute
// MFMA B-fragments (6 adj + 16 wcat-hi + 16 wcat-lo) in per-lane order so
// sage loads them straight into VGPRs, coalesced. Same f2bf RNE as R10.
// ---------------------------------------------------------------------------
__global__ void prep_kernel(const float* __restrict__ Wih0, const float* __restrict__ Whh0,
                            const float* __restrict__ Wih1, const float* __restrict__ Whh1,
                            const float* __restrict__ adjn,
                            const float* __restrict__ Ws2, const float* __restrict__ Wn2,
                            float* __restrict__ Wih0T, float* __restrict__ Whh0T,
                            float* __restrict__ Wih1T, float* __restrict__ Whh1T,
                            short* __restrict__ adjfG, short* __restrict__ wcatfG) {
    int bid = blockIdx.x, tid = threadIdx.x;
    if (bid >= 896) {
        int t = (bid - 896) * 256 + tid;                  // 0..2559, use 2432
        if (t >= 2432) return;
        int f = t >> 6, l = t & 63;
        int q = l >> 4, l15 = l & 15;
        short8 v;
        if (f < 6) {                                      // adj frags (nt,ks) pairs
            const int ntT[6] = {0, 1, 1, 2, 2, 3};
            const int ksT[6] = {0, 0, 1, 0, 1, 1};
            int row = l15 + 16 * ntT[f], col = 8 * q + 32 * ksT[f];
            #pragma unroll
            for (int e = 0; e < 8; ++e)
                v[e] = f2bf(adjn[row * 64 + col + e]);
            *(short8*)(adjfG + ((size_t)f * 64 + l) * 8) = v;
        } else {                                          // wcat hi (fi<16) / lo
            int fi = f - 6;
            int isLo = fi >= 16;
            int ff = isLo ? fi - 16 : fi;
            int nt = ff >> 2, ks = ff & 3;
            int oo = l15 + 16 * nt;
            #pragma unroll
            for (int e = 0; e < 8; ++e) {
                int k = 32 * ks + 8 * q + e;
                float src = (k < 64) ? Ws2[oo * 64 + k] : Wn2[oo * 64 + (k - 64)];
                short hi = f2bf(src);
                v[e] = isLo ? f2bf(src - bf2f(hi)) : hi;
            }
            *(short8*)(wcatfG + ((size_t)fi * 64 + l) * 8) = v;
        }
        return;
    }
    int e = bid * 256 + tid;
    if (e < 32768) {
        int k = e >> 9, j = e & 511;
        Wih0T[e] = Wih0[j * 64 + k];
    } else if (e < 98304) {
        int q = e - 32768; int k = q >> 9, j = q & 511;
        Whh0T[q] = Whh0[j * 128 + k];
    } else if (e < 163840) {
        int q = e - 98304; int k = q >> 9, j = q & 511;
        Wih1T[q] = Wih1[j * 128 + k];
    } else if (e < 229376) {
        int q = e - 163840; int k = q >> 9, j = q & 511;
        Whh1T[q] = Whh1[j * 128 + k];
    }
}

// ---------------------------------------------------------------------------
// Persistent fused SAGE via bf16 MFMA: 512 blocks x 62 patches. All B-operand
// fragments (adj, W hi/lo) live in VGPRs for the kernel lifetime; LDS holds
// only patch-local x1T/cat (29 KB). Numerics bit-identical to R10.
// ---------------------------------------------------------------------------
__launch_bounds__(256, 2)
__global__ void sage_mfma(const float* __restrict__ I, const float* __restrict__ Q,
                          const float* __restrict__ adjn,
                          const float* __restrict__ Wn1, const float* __restrict__ bn1,
                          const float* __restrict__ Ws1, const float* __restrict__ bs1,
                          const float* __restrict__ bn2, const float* __restrict__ bs2,
                          const short* __restrict__ adjfG, const short* __restrict__ wcatfG,
                          float* __restrict__ feats) {
    __shared__ __align__(16) short s_x1T[64 * X1TS];   // x1^T [o][i] bf16
    __shared__ __align__(16) short s_cat[64 * CAS];    // [i][0..63:x1, 64..127:n1] bf16
    __shared__ __align__(16) float s_x0[128];
    __shared__ __align__(16) float s_n0[128];
    __shared__ __align__(16) float s_part[4][64];

    const int tid = threadIdx.x;
    const int w = tid >> 6, l = tid & 63, q = l >> 4, l15 = l & 15;

    // ---- lifetime VGPR fragments (patch- and wave-invariant) ----
    short8 adjf[6];
    #pragma unroll
    for (int f = 0; f < 6; ++f)
        adjf[f] = *(const short8*)(adjfG + ((size_t)f * 64 + l) * 8);
    short8 whf[16], wlf[16];
    #pragma unroll
    for (int f = 0; f < 16; ++f) {
        whf[f] = *(const short8*)(wcatfG + ((size_t)f * 64 + l) * 8);
        wlf[f] = *(const short8*)(wcatfG + ((size_t)(f + 16) * 64 + l) * 8);
    }

    for (int it = 0; it < 62; ++it) {
        const int m = blockIdx.x + it * 512;
        const int b = m / PNUM, p = m % PNUM;
        const float* Ibase = I + (size_t)b * L_SZ + p * STRIDE_;
        const float* Qbase = Q + (size_t)b * L_SZ + p * STRIDE_;

        // ---- stage x0 ----
        if (tid < 128) {
            int i = tid >> 1, ch = tid & 1;
            s_x0[i * 2 + ch] = ch ? Qbase[i] : Ibase[i];
        }
        __syncthreads();

        // ---- Phase 1a: n0[i][ch] (exact fp32 adj from global, L2-resident) ----
        if (tid < 128) {
            int i = tid >> 1, ch = tid & 1;
            int jlo = i - WIN; if (jlo < 0) jlo = 0;
            int jhi = i + WIN; if (jhi > 63) jhi = 63;
            float acc = 0.f;
            for (int j = jlo; j <= jhi; ++j)
                acc += adjn[i * 64 + j] * s_x0[j * 2 + ch];
            s_n0[i * 2 + ch] = acc;
        }
        __syncthreads();

        // ---- Phase 1b: x1[i][o] = relu(...), write x1T (scalar) + catA (b128) ----
        {
            int i = tid & 63, oc = tid >> 6;
            float x0a = s_x0[i * 2], x0b = s_x0[i * 2 + 1];
            float n0a = s_n0[i * 2], n0b = s_n0[i * 2 + 1];
            union { short s[16]; short8 v[2]; } pk;
            #pragma unroll
            for (int t = 0; t < 16; ++t) {
                int o = oc * 16 + t;                     // wave-uniform -> s_load
                float2 wsv = ((const float2*)Ws1)[o];
                float2 wnv = ((const float2*)Wn1)[o];
                float v = bs1[o] + bn1[o] + wsv.x * x0a + wsv.y * x0b
                                          + wnv.x * n0a + wnv.y * n0b;
                v = fmaxf(v, 0.f);
                short bv = f2bf(v);
                s_x1T[o * X1TS + i] = bv;                // transposed copy
                pk.s[t] = bv;
            }
            *(short8*)&s_cat[i * CAS + oc * 16]     = pk.v[0];
            *(short8*)&s_cat[i * CAS + oc * 16 + 8] = pk.v[1];
        }
        __syncthreads();

        // ---- MFMA#1: n1^T, band-aware (6 tiles), B-frags from VGPRs ----
        {
            short8 a0 = *(const short8*)&s_x1T[(16 * w + l15) * X1TS + 8 * q];
            short8 a1 = *(const short8*)&s_x1T[(16 * w + l15) * X1TS + 8 * q + 32];
            f32x4 z = {0.f, 0.f, 0.f, 0.f};
            f32x4 c0 = z, c1 = z, c2 = z, c3 = z;
            c0 = MFMA16(a0, adjf[0], c0);
            c1 = MFMA16(a0, adjf[1], c1);
            c1 = MFMA16(a1, adjf[2], c1);
            c2 = MFMA16(a0, adjf[3], c2);
            c2 = MFMA16(a1, adjf[4], c2);
            c3 = MFMA16(a1, adjf[5], c3);
            f32x4 cc[4] = {c0, c1, c2, c3};
            #pragma unroll
            for (int nt = 0; nt < 4; ++nt) {
                short4v nv;
                nv[0] = f2bf(cc[nt][0]); nv[1] = f2bf(cc[nt][1]);
                nv[2] = f2bf(cc[nt][2]); nv[3] = f2bf(cc[nt][3]);
                *(short4v*)&s_cat[(l15 + 16 * nt) * CAS + 64 + 16 * w + 4 * q] = nv;
            }
        }
        __syncthreads();

        // ---- MFMA#2: out2 tile; B = W_hi + W_lo from VGPRs ----
        {
            short8 a2[4];
            #pragma unroll
            for (int ks = 0; ks < 4; ++ks)
                a2[ks] = *(const short8*)&s_cat[(16 * w + l15) * CAS + 32 * ks + 8 * q];
            f32x4 z = {0.f, 0.f, 0.f, 0.f};
            f32x4 acc2[4] = {z, z, z, z};
            #pragma unroll
            for (int nt = 0; nt < 4; ++nt) {
                #pragma unroll
                for (int ks = 0; ks < 4; ++ks) {
                    acc2[nt] = MFMA16(a2[ks], whf[nt * 4 + ks], acc2[nt]);
                    acc2[nt] = MFMA16(a2[ks], wlf[nt * 4 + ks], acc2[nt]);
                }
            }
            float part[4];
            #pragma unroll
            for (int nt = 0; nt < 4; ++nt) {
                int oo = l15 + 16 * nt;
                float bo = bs2[oo] + bn2[oo];
                float s = fmaxf(acc2[nt][0] + bo, 0.f) + fmaxf(acc2[nt][1] + bo, 0.f)
                        + fmaxf(acc2[nt][2] + bo, 0.f) + fmaxf(acc2[nt][3] + bo, 0.f);
                s += __shfl_xor(s, 16);
                s += __shfl_xor(s, 32);
                part[nt] = s;
            }
            if (l < 16) {
                #pragma unroll
                for (int nt = 0; nt < 4; ++nt)
                    s_part[w][l + 16 * nt] = part[nt];
            }
        }
        __syncthreads();
        if (tid < 64)
            feats[(size_t)m * 64 + tid] =
                s_part[0][tid] + s_part[1][tid] + s_part[2][tid] + s_part[3][tid];
    }
}

// ---------------------------------------------------------------------------
// LSTM layer 0 v2 (unchanged from R10): 512 thr, one gate/thread.
// ---------------------------------------------------------------------------
__launch_bounds__(512)
__global__ void lstm0_fused(const float* __restrict__ feats,
                            const float* __restrict__ WihT, const float* __restrict__ WhhT,
                            const float* __restrict__ bih, const float* __restrict__ bhh,
                            float* __restrict__ out0) {
    __shared__ __align__(16) float s_xf[64 * 4];    // [k][r]
    __shared__ __align__(16) float s_hf[128 * 4];   // [k][r]
    __shared__ float s_c[4][128];
    __shared__ float s_g[4][512];
    const int tid = threadIdx.x;
    const int b0 = blockIdx.x * 4;

    s_hf[tid] = 0.f;
    { int r = tid >> 7, u = tid & 127; s_c[r][u] = 0.f; }
    const float bias = bih[tid] + bhh[tid];
    __syncthreads();

    for (int t = 0; t < 31; ++t) {
        if (tid < 256) {
            int r = tid >> 6, d = tid & 63;
            s_xf[d * 4 + r] = feats[((size_t)(b0 + r) * PNUM + t) * 64 + d];
        }
        __syncthreads();

        float a0 = bias, a1 = bias, a2 = bias, a3 = bias;
        const float* wp = WihT + tid;
        #pragma unroll 8
        for (int k = 0; k < 64; ++k) {
            float wv = wp[(size_t)k * 512];
            float4 xv = *(const float4*)&s_xf[k * 4];
            a0 += xv.x * wv; a1 += xv.y * wv; a2 += xv.z * wv; a3 += xv.w * wv;
        }
        const float* hp = WhhT + tid;
        #pragma unroll 8
        for (int k = 0; k < 128; ++k) {
            float wv = hp[(size_t)k * 512];
            float4 hv = *(const float4*)&s_hf[k * 4];
            a0 += hv.x * wv; a1 += hv.y * wv; a2 += hv.z * wv; a3 += hv.w * wv;
        }
        s_g[0][tid] = a0; s_g[1][tid] = a1; s_g[2][tid] = a2; s_g[3][tid] = a3;
        __syncthreads();

        {
            int r = tid >> 7, u = tid & 127;
            float gi = s_g[r][u], gf = s_g[r][128 + u];
            float gg = s_g[r][256 + u], go = s_g[r][384 + u];
            float c = sigf(gf) * s_c[r][u] + sigf(gi) * tanhfast(gg);
            float h = sigf(go) * tanhfast(c);
            s_c[r][u] = c;
            s_hf[u * 4 + r] = h;
            out0[((size_t)(b0 + r) * PNUM + t) * 128 + u] = h;
        }
        __syncthreads();
    }
}

// ---------------------------------------------------------------------------
// LSTM layer 1 v2 + classifier (unchanged from R10). fp32 out [B,11].
// ---------------------------------------------------------------------------
__launch_bounds__(512)
__global__ void lstm1_fused(const float* __restrict__ out0,
                            const float* __restrict__ WihT, const float* __restrict__ WhhT,
                            const float* __restrict__ bih, const float* __restrict__ bhh,
                            const float* __restrict__ Wc1, const float* __restrict__ bc1,
                            const float* __restrict__ Wc2, const float* __restrict__ bc2,
                            float* __restrict__ out) {
    __shared__ __align__(16) float s_xf[128 * 4];   // [k][r]
    __shared__ __align__(16) float s_hf[128 * 4];   // [k][r]
    __shared__ float s_c[4][128];
    __shared__ float s_g[4][512];
    __shared__ float s_hid[4][64];
    const int tid = threadIdx.x;
    const int b0 = blockIdx.x * 4;

    s_hf[tid] = 0.f;
    { int r = tid >> 7, u = tid & 127; s_c[r][u] = 0.f; }
    const float bias = bih[tid] + bhh[tid];
    __syncthreads();

    for (int t = 0; t < 31; ++t) {
        {
            int r = tid >> 7, k = tid & 127;
            s_xf[k * 4 + r] = out0[((size_t)(b0 + r) * PNUM + t) * 128 + k];
        }
        __syncthreads();

        float a0 = bias, a1 = bias, a2 = bias, a3 = bias;
        const float* wp = WihT + tid;
        #pragma unroll 8
        for (int k = 0; k < 128; ++k) {
            float wv = wp[(size_t)k * 512];
            float4 xv = *(const float4*)&s_xf[k * 4];
            a0 += xv.x * wv; a1 += xv.y * wv; a2 += xv.z * wv; a3 += xv.w * wv;
        }
        const float* hp = WhhT + tid;
        #pragma unroll 8
        for (int k = 0; k < 128; ++k) {
            float wv = hp[(size_t)k * 512];
            float4 hv = *(const float4*)&s_hf[k * 4];
            a0 += hv.x * wv; a1 += hv.y * wv; a2 += hv.z * wv; a3 += hv.w * wv;
        }
        s_g[0][tid] = a0; s_g[1][tid] = a1; s_g[2][tid] = a2; s_g[3][tid] = a3;
        __syncthreads();

        {
            int r = tid >> 7, u = tid & 127;
            float gi = s_g[r][u], gf = s_g[r][128 + u];
            float gg = s_g[r][256 + u], go = s_g[r][384 + u];
            float c = sigf(gf) * s_c[r][u] + sigf(gi) * tanhfast(gg);
            float h = sigf(go) * tanhfast(c);
            s_c[r][u] = c;
            s_hf[u * 4 + r] = h;
        }
        __syncthreads();
    }

    if (tid < 256) {
        int r = tid >> 6, u = tid & 63;
        float acc = bc1[u];
        const float* wv = Wc1 + (size_t)u * 128;
        #pragma unroll 8
        for (int k = 0; k < 128; ++k) acc += wv[k] * s_hf[k * 4 + r];
        s_hid[r][u] = fmaxf(acc, 0.f);
    }
    __syncthreads();
    if (tid < 44) {
        int r = tid / 11, c = tid % 11;
        float acc = bc2[c];
        #pragma unroll
        for (int u = 0; u < 64; ++u) acc += Wc2[c * 64 + u] * s_hid[r][u];
        out[(size_t)(b0 + r) * 11 + c] = acc;
    }
}

// ---------------------------------------------------------------------------
extern "C" void kernel_launch(void* const* d_in, const int* in_sizes, int n_in,
                              void* d_out, int out_size, void* d_ws, size_t ws_size,
                              hipStream_t stream) {
    (void)in_sizes; (void)n_in; (void)out_size; (void)ws_size;
    const float* I    = (const float*)d_in[0];
    const float* Q    = (const float*)d_in[1];
    const float* ew   = (const float*)d_in[2];
    const float* Wn1  = (const float*)d_in[3];
    const float* bn1  = (const float*)d_in[4];
    const float* Ws1  = (const float*)d_in[5];
    const float* bs1  = (const float*)d_in[6];
    const float* Wn2  = (const float*)d_in[7];
    const float* bn2  = (const float*)d_in[8];
    const float* Ws2  = (const float*)d_in[9];
    const float* bs2  = (const float*)d_in[10];
    const float* Wih0 = (const float*)d_in[11];
    const float* Whh0 = (const float*)d_in[12];
    const float* bih0 = (const float*)d_in[13];
    const float* bhh0 = (const float*)d_in[14];
    const float* Wih1 = (const float*)d_in[15];
    const float* Whh1 = (const float*)d_in[16];
    const float* bih1 = (const float*)d_in[17];
    const float* bhh1 = (const float*)d_in[18];
    const float* Wc1  = (const float*)d_in[19];
    const float* bc1  = (const float*)d_in[20];
    const float* Wc2  = (const float*)d_in[21];
    const float* bc2  = (const float*)d_in[22];
    float* out = (float*)d_out;

    // workspace (floats): adjn 4096 | WihT0 32768 | WhhT0 65536 | WihT1 65536
    //   | WhhT1 65536 | frag region 9728 (adjf 3072 + wcatf 16384 shorts) | feats | out0
    float* wsp   = (float*)d_ws;
    float* adjn  = wsp;
    float* WihT0 = adjn  + 4096;
    float* WhhT0 = WihT0 + 32768;
    float* WihT1 = WhhT0 + 65536;
    float* WhhT1 = WihT1 + 65536;
    short* adjfG  = (short*)(WhhT1 + 65536);      // 3072 shorts, 16B-aligned
    short* wcatfG = adjfG + 3072;                 // 16384 shorts
    float* feats = WhhT1 + 65536 + 9728;
    float* out0  = feats + 2031616;

    adj_kernel<<<1, 64, 0, stream>>>(ew, adjn);
    prep_kernel<<<906, 256, 0, stream>>>(Wih0, Whh0, Wih1, Whh1, adjn, Ws2, Wn2,
                                         WihT0, WhhT0, WihT1, WhhT1, adjfG, wcatfG);
    sage_mfma<<<512, 256, 0, stream>>>(I, Q, adjn, Wn1, bn1, Ws1, bs1,
                                       bn2, bs2, adjfG, wcatfG, feats);
    lstm0_fused<<<256, 512, 0, stream>>>(feats, WihT0, WhhT0, bih0, bhh0, out0);
    lstm1_fused<<<256, 512, 0, stream>>>(out0, WihT1, WhhT1, bih1, bhh1,
                                         Wc1, bc1, Wc2, bc2, out);
}